// Round 9
// baseline (75.915 us; speedup 1.0000x reference)
//
#include <hip/hip_runtime.h>
#include <hip/hip_bf16.h>

#define B_   32
#define S_   2048
#define D_   64
#define KVB  64
#define NP   16            // pair-iterations: 2 kv tiles (128 rows) each
#define QB   256           // q rows per block

typedef __attribute__((ext_vector_type(8)))  __bf16 bf16x8;
typedef __attribute__((ext_vector_type(4)))  __bf16 bf16x4;
typedef __attribute__((ext_vector_type(16))) float  f32x16;

__device__ __forceinline__ float fexp2(float x) {
#if __has_builtin(__builtin_amdgcn_exp2f)
    return __builtin_amdgcn_exp2f(x);
#else
    return exp2f(x);
#endif
}

__device__ __forceinline__ unsigned pk2(float a, float b) {
    unsigned r;
    asm("v_cvt_pk_bf16_f32 %0, %1, %2" : "=v"(r) : "v"(a), "v"(b));
    return r;
}

__device__ __forceinline__ void pl32swap(unsigned &a, unsigned &b) {
#if __has_builtin(__builtin_amdgcn_permlane32_swap)
    auto r = __builtin_amdgcn_permlane32_swap(a, b, false, false);
    a = (unsigned)r[0]; b = (unsigned)r[1];
#else
    unsigned pa = (unsigned)__shfl_xor((int)a, 32);
    unsigned pb = (unsigned)__shfl_xor((int)b, 32);
    bool hi = (threadIdx.x & 32) != 0;
    unsigned na = hi ? pb : a;
    unsigned nb = hi ? b  : pa;
    a = na; b = nb;
#endif
}

struct PBpair { bf16x8 a, b; };

// Build two PV B-fragments (kv chunks of 16) from one 32-kv score tile.
// Lane layout in: ps[r] = P[q=lane&31][kv32 = (r&3)+8*(r>>2)+4*(lane>>5)].
__device__ __forceinline__ PBpair pack2(const f32x16 ps) {
    unsigned y0 = pk2(ps[0],  ps[1]);
    unsigned y1 = pk2(ps[2],  ps[3]);
    unsigned y2 = pk2(ps[4],  ps[5]);
    unsigned y3 = pk2(ps[6],  ps[7]);
    pl32swap(y0, y2); pl32swap(y1, y3);
    unsigned z0 = pk2(ps[8],  ps[9]);
    unsigned z1 = pk2(ps[10], ps[11]);
    unsigned z2 = pk2(ps[12], ps[13]);
    unsigned z3 = pk2(ps[14], ps[15]);
    pl32swap(z0, z2); pl32swap(z1, z3);
    union { unsigned u[4]; bf16x8 v; } pa, pbu;
    pa.u[0]=y0;  pa.u[1]=y1;  pa.u[2]=y2;  pa.u[3]=y3;
    pbu.u[0]=z0; pbu.u[1]=z1; pbu.u[2]=z2; pbu.u[3]=z3;
    PBpair r; r.a = pa.v; r.b = pbu.v; return r;
}

__global__ __launch_bounds__(512, 2)
void attn_fwd(const float* __restrict__ Q, const float* __restrict__ K,
              const float* __restrict__ V, float* __restrict__ Out)
{
    // triple-buffered PAIRS of K / V^T tiles: [buf][tile-in-pair][tile]; 96 KiB
    __shared__ __align__(16) __bf16 Kt[3][2][KVB * D_];
    __shared__ __align__(16) __bf16 Vt[3][2][D_ * KVB];

    const int tid  = threadIdx.x;
    const int w    = tid >> 6;
    const int lane = tid & 63;
    const int l31  = lane & 31;
    const int hi   = lane >> 5;
    const int g2   = w >> 2;           // kv-group: 0 = even tile of pair, 1 = odd
    const int qsub = w & 3;            // 64-row q slice within the block

    const int bid = blockIdx.x;
    const int swz = ((bid & 7) << 5) | (bid >> 3);   // bijective XCD swizzle (256 blocks)
    const int b   = swz >> 3;
    const int q0  = (swz & 7) * QB;

    // ---- Q fragments for BOTH 32-row q-tiles; scale (1/8)*log2(e) folded ----
    const float SCL = 0.18033688011112042f;
    bf16x8 qfA[4], qfB[4];
    #pragma unroll
    for (int qt = 0; qt < 2; ++qt) {
        const float* qp = Q + ((size_t)(b*S_ + q0 + qsub*64 + qt*32 + l31))*D_ + hi*8;
        #pragma unroll
        for (int ks = 0; ks < 4; ++ks) {
            float4 f0 = *reinterpret_cast<const float4*>(qp + ks*16);
            float4 f1 = *reinterpret_cast<const float4*>(qp + ks*16 + 4);
            bf16x8 a;
            a[0]=(__bf16)(f0.x*SCL); a[1]=(__bf16)(f0.y*SCL);
            a[2]=(__bf16)(f0.z*SCL); a[3]=(__bf16)(f0.w*SCL);
            a[4]=(__bf16)(f1.x*SCL); a[5]=(__bf16)(f1.y*SCL);
            a[6]=(__bf16)(f1.z*SCL); a[7]=(__bf16)(f1.w*SCL);
            if (qt == 0) qfA[ks]=a; else qfB[ks]=a;
        }
    }

    // per-lane LDS read offsets: K rows use (row&7), V^T rows use ((d>>1)&7)
    int offK[4], offV[4];
    #pragma unroll
    for (int i = 0; i < 4; ++i) {
        offK[i] = l31*128 + (((i*32) + hi*16) ^ ((l31 & 7) << 4));
        offV[i] = l31*128 + (((i*32) + hi*16) ^ (((l31 >> 1) & 7) << 4));
    }

    // ---- staging geometry: 512 threads stage a PAIR of 64x64 K and V tiles ----
    const float* kg = K + (size_t)b*S_*D_;
    const float* vg = V + (size_t)b*S_*D_;

    const int ts   = tid >> 8;                  // which tile of the pair this thread stages
    const int t256 = tid & 255;

    const int krow0 = t256 >> 4;                // 0..15 (rows +0,16,32,48)
    const int kcol  = (t256 & 15) * 4;          // float col
    const int kwr0  = krow0*128 + ((kcol*2) ^ ((krow0 & 7) << 4));

    const int kv0 = (t256 >> 4) * 2;            // 0..30 (and +32)
    const int db  = (t256 & 15) * 2;            // 0..30 (and +32)
    int vwr[4];
    #pragma unroll
    for (int j = 0; j < 4; ++j) {
        int d = db + (j >> 1)*32 + (j & 1);     // db, db+1, db+32, db+33
        vwr[j] = d*128 + ((kv0*2) ^ (((d >> 1) & 7) << 4));
    }

#define STAGE_LOAD(P)                                                              \
    {   const float* kt_ = kg + ((size_t)(P)*128 + ts*64)*64;                      \
        const float* vt_ = vg + ((size_t)(P)*128 + ts*64)*64;                      \
        ka0 = *reinterpret_cast<const float4*>(kt_ + krow0*64 + kcol);             \
        ka1 = *reinterpret_cast<const float4*>(kt_ + (krow0+16)*64 + kcol);        \
        ka2 = *reinterpret_cast<const float4*>(kt_ + (krow0+32)*64 + kcol);        \
        ka3 = *reinterpret_cast<const float4*>(kt_ + (krow0+48)*64 + kcol);        \
        v0a = *reinterpret_cast<const float2*>(vt_ + kv0*64 + db);                 \
        v1a = *reinterpret_cast<const float2*>(vt_ + (kv0+1)*64 + db);             \
        v0b = *reinterpret_cast<const float2*>(vt_ + kv0*64 + db + 32);            \
        v1b = *reinterpret_cast<const float2*>(vt_ + (kv0+1)*64 + db + 32);        \
        v2a = *reinterpret_cast<const float2*>(vt_ + (kv0+32)*64 + db);            \
        v3a = *reinterpret_cast<const float2*>(vt_ + (kv0+33)*64 + db);            \
        v2b = *reinterpret_cast<const float2*>(vt_ + (kv0+32)*64 + db + 32);       \
        v3b = *reinterpret_cast<const float2*>(vt_ + (kv0+33)*64 + db + 32);       }

#define STAGE_WRITE(BUF)                                                           \
    {   char* kw = (char*)&Kt[(BUF)][ts][0];                                       \
        char* vw = (char*)&Vt[(BUF)][ts][0];                                       \
        bf16x4 h0 = {(__bf16)ka0.x,(__bf16)ka0.y,(__bf16)ka0.z,(__bf16)ka0.w};     \
        bf16x4 h1 = {(__bf16)ka1.x,(__bf16)ka1.y,(__bf16)ka1.z,(__bf16)ka1.w};     \
        bf16x4 h2 = {(__bf16)ka2.x,(__bf16)ka2.y,(__bf16)ka2.z,(__bf16)ka2.w};     \
        bf16x4 h3 = {(__bf16)ka3.x,(__bf16)ka3.y,(__bf16)ka3.z,(__bf16)ka3.w};     \
        *reinterpret_cast<bf16x4*>(kw + kwr0)        = h0;                         \
        *reinterpret_cast<bf16x4*>(kw + kwr0 + 2048) = h1;                         \
        *reinterpret_cast<bf16x4*>(kw + kwr0 + 4096) = h2;                         \
        *reinterpret_cast<bf16x4*>(kw + kwr0 + 6144) = h3;                         \
        *reinterpret_cast<unsigned*>(vw + vwr[0])        = pk2(v0a.x, v1a.x);      \
        *reinterpret_cast<unsigned*>(vw + vwr[1])        = pk2(v0a.y, v1a.y);      \
        *reinterpret_cast<unsigned*>(vw + vwr[2])        = pk2(v0b.x, v1b.x);      \
        *reinterpret_cast<unsigned*>(vw + vwr[3])        = pk2(v0b.y, v1b.y);      \
        *reinterpret_cast<unsigned*>(vw + (vwr[0] ^ 64)) = pk2(v2a.x, v3a.x);      \
        *reinterpret_cast<unsigned*>(vw + (vwr[1] ^ 64)) = pk2(v2a.y, v3a.y);      \
        *reinterpret_cast<unsigned*>(vw + (vwr[2] ^ 64)) = pk2(v2b.x, v3b.x);      \
        *reinterpret_cast<unsigned*>(vw + (vwr[3] ^ 64)) = pk2(v2b.y, v3b.y);      }

    float4 ka0, ka1, ka2, ka3;
    float2 v0a, v1a, v0b, v1b, v2a, v3a, v2b, v3b;

    // persistent zero vector: MFMA C-operand for the first K-slice (no re-zeroing)
    f32x16 ZV;
    #pragma unroll
    for (int i = 0; i < 16; ++i) ZV[i] = 0.f;

    float lA = 0.f, lB = 0.f;
    f32x16 oA0 = ZV, oA1 = ZV, oB0 = ZV, oB1 = ZV;
    PBpair pA01, pA23, pB01, pB23;

#define QK_BOTH(KBUF)                                                              \
    {   const char* kbuf = (const char*)&Kt[(KBUF)][g2][0];                        \
        __builtin_amdgcn_s_setprio(1);                                             \
        {   bf16x8 k0 = *reinterpret_cast<const bf16x8*>(kbuf + offK[0]);          \
            bf16x8 k1 = *reinterpret_cast<const bf16x8*>(kbuf + offK[0] + 4096);   \
            sA0 = __builtin_amdgcn_mfma_f32_32x32x16_bf16(k0, qfA[0], ZV, 0,0,0);  \
            sB0 = __builtin_amdgcn_mfma_f32_32x32x16_bf16(k0, qfB[0], ZV, 0,0,0);  \
            sA1 = __builtin_amdgcn_mfma_f32_32x32x16_bf16(k1, qfA[0], ZV, 0,0,0);  \
            sB1 = __builtin_amdgcn_mfma_f32_32x32x16_bf16(k1, qfB[0], ZV, 0,0,0);  \
        }                                                                          \
        _Pragma("unroll")                                                          \
        for (int ks = 1; ks < 4; ++ks) {                                           \
            bf16x8 k0 = *reinterpret_cast<const bf16x8*>(kbuf + offK[ks]);         \
            bf16x8 k1 = *reinterpret_cast<const bf16x8*>(kbuf + offK[ks] + 4096);  \
            sA0 = __builtin_amdgcn_mfma_f32_32x32x16_bf16(k0, qfA[ks], sA0, 0,0,0);\
            sB0 = __builtin_amdgcn_mfma_f32_32x32x16_bf16(k0, qfB[ks], sB0, 0,0,0);\
            sA1 = __builtin_amdgcn_mfma_f32_32x32x16_bf16(k1, qfA[ks], sA1, 0,0,0);\
            sB1 = __builtin_amdgcn_mfma_f32_32x32x16_bf16(k1, qfB[ks], sB1, 0,0,0);\
        }                                                                          \
        __builtin_amdgcn_s_setprio(0);                                             }

#define PV_BOTH(VBUF)                                                              \
    {   const char* vbuf = (const char*)&Vt[(VBUF)][g2][0];                        \
        __builtin_amdgcn_s_setprio(1);                                             \
        _Pragma("unroll")                                                          \
        for (int c = 0; c < 4; ++c) {                                              \
            bf16x8 pa = (c==0)?pA01.a:(c==1)?pA01.b:(c==2)?pA23.a:pA23.b;          \
            bf16x8 pb = (c==0)?pB01.a:(c==1)?pB01.b:(c==2)?pB23.a:pB23.b;          \
            bf16x8 v0 = *reinterpret_cast<const bf16x8*>(vbuf + offV[c]);          \
            bf16x8 v1 = *reinterpret_cast<const bf16x8*>(vbuf + offV[c] + 4096);   \
            oA0 = __builtin_amdgcn_mfma_f32_32x32x16_bf16(v0, pa, oA0, 0,0,0);     \
            oB0 = __builtin_amdgcn_mfma_f32_32x32x16_bf16(v0, pb, oB0, 0,0,0);     \
            oA1 = __builtin_amdgcn_mfma_f32_32x32x16_bf16(v1, pa, oA1, 0,0,0);     \
            oB1 = __builtin_amdgcn_mfma_f32_32x32x16_bf16(v1, pb, oB1, 0,0,0);     \
        }                                                                          \
        __builtin_amdgcn_s_setprio(0);                                             }

#define SOFTMAX_PACK()                                                             \
    {   _Pragma("unroll")                                                          \
        for (int r = 0; r < 16; ++r) sA0[r] = fexp2(sA0[r]);                       \
        _Pragma("unroll")                                                          \
        for (int r = 0; r < 16; ++r) sA1[r] = fexp2(sA1[r]);                       \
        _Pragma("unroll")                                                          \
        for (int r = 0; r < 16; ++r) sB0[r] = fexp2(sB0[r]);                       \
        _Pragma("unroll")                                                          \
        for (int r = 0; r < 16; ++r) sB1[r] = fexp2(sB1[r]);                       \
        float tA[16], tB[16];                                                      \
        _Pragma("unroll")                                                          \
        for (int i = 0; i < 16; ++i) { tA[i] = sA0[i] + sA1[i];                    \
                                       tB[i] = sB0[i] + sB1[i]; }                  \
        _Pragma("unroll")                                                          \
        for (int st = 8; st > 0; st >>= 1)                                         \
            _Pragma("unroll")                                                      \
            for (int i = 0; i < st; ++i) { tA[i] += tA[i+st]; tB[i] += tB[i+st]; } \
        lA += tA[0] + __shfl_xor(tA[0], 32);                                       \
        lB += tB[0] + __shfl_xor(tB[0], 32);                                       \
        pA01 = pack2(sA0); pA23 = pack2(sA1);                                      \
        pB01 = pack2(sB0); pB23 = pack2(sB1);                                      }

    // ---- prologue: stage pair 0 ----
    STAGE_LOAD(0)
    STAGE_WRITE(0)
    __syncthreads();

    // ---- p = 0: QK + softmax + pack; stage pair 1 ----
    {
        STAGE_LOAD(1)
        f32x16 sA0, sA1, sB0, sB1;
        QK_BOTH(0)
        SOFTMAX_PACK()
        STAGE_WRITE(1)
        __syncthreads();
    }

    // ---- pipelined main loop over tile pairs ----
    for (int p = 1; p < NP; ++p) {
        const int cur = p % 3;
        const int prv = (p-1) % 3;
        const int nxt = (p+1) % 3;
        STAGE_LOAD(p+1 < NP ? p+1 : p)

        f32x16 sA0, sA1, sB0, sB1;
        QK_BOTH(cur)
        PV_BOTH(prv)          // previous pair's P: independent of s*, overlaps softmax
        SOFTMAX_PACK()

        STAGE_WRITE(nxt)
        __syncthreads();
    }

    // ---- last PV ----
    PV_BOTH((NP-1) % 3)

    // ---- merge the two kv-groups through LDS (fixed-m: partials just add) ----
    float* M = reinterpret_cast<float*>(&Kt[0][0][0]);   // reuse: 256 x 33 f32
    const int mqA = qsub*64 + l31;
    const int mqB = mqA + 32;
    float invlA = 0.f, invlB = 0.f;

    // chunk 0: d 0..31 (oA0, oB0) + l
    if (g2 == 1) {
        #pragma unroll
        for (int rr = 0; rr < 4; ++rr)
            #pragma unroll
            for (int j = 0; j < 4; ++j) {
                M[mqA*33 + rr*8 + hi*4 + j] = oA0[rr*4+j];
                M[mqB*33 + rr*8 + hi*4 + j] = oB0[rr*4+j];
            }
        if (hi == 0) { M[mqA*33 + 32] = lA; M[mqB*33 + 32] = lB; }
    }
    __syncthreads();
    if (g2 == 0) {
        lA += M[mqA*33 + 32];
        lB += M[mqB*33 + 32];
        invlA = 1.0f / lA; invlB = 1.0f / lB;
        float* orowA = Out + ((size_t)(b*S_ + q0 + mqA))*D_;
        float* orowB = Out + ((size_t)(b*S_ + q0 + mqB))*D_;
        #pragma unroll
        for (int rr = 0; rr < 4; ++rr) {
            float4 ra, rb;
            ra.x = (oA0[rr*4+0] + M[mqA*33 + rr*8 + hi*4 + 0]) * invlA;
            ra.y = (oA0[rr*4+1] + M[mqA*33 + rr*8 + hi*4 + 1]) * invlA;
            ra.z = (oA0[rr*4+2] + M[mqA*33 + rr*8 + hi*4 + 2]) * invlA;
            ra.w = (oA0[rr*4+3] + M[mqA*33 + rr*8 + hi*4 + 3]) * invlA;
            rb.x = (oB0[rr*4+0] + M[mqB*33 + rr*8 + hi*4 + 0]) * invlB;
            rb.y = (oB0[rr*4+1] + M[mqB*33 + rr*8 + hi*4 + 1]) * invlB;
            rb.z = (oB0[rr*4+2] + M[mqB*33 + rr*8 + hi*4 + 2]) * invlB;
            rb.w = (oB0[rr*4+3] + M[mqB*33 + rr*8 + hi*4 + 3]) * invlB;
            *reinterpret_cast<float4*>(orowA + rr*8 + hi*4) = ra;
            *reinterpret_cast<float4*>(orowB + rr*8 + hi*4) = rb;
        }
    }
    __syncthreads();
    // chunk 1: d 32..63 (oA1, oB1)
    if (g2 == 1) {
        #pragma unroll
        for (int rr = 0; rr < 4; ++rr)
            #pragma unroll
            for (int j = 0; j < 4; ++j) {
                M[mqA*33 + rr*8 + hi*4 + j] = oA1[rr*4+j];
                M[mqB*33 + rr*8 + hi*4 + j] = oB1[rr*4+j];
            }
    }
    __syncthreads();
    if (g2 == 0) {
        float* orowA = Out + ((size_t)(b*S_ + q0 + mqA))*D_ + 32;
        float* orowB = Out + ((size_t)(b*S_ + q0 + mqB))*D_ + 32;
        #pragma unroll
        for (int rr = 0; rr < 4; ++rr) {
            float4 ra, rb;
            ra.x = (oA1[rr*4+0] + M[mqA*33 + rr*8 + hi*4 + 0]) * invlA;
            ra.y = (oA1[rr*4+1] + M[mqA*33 + rr*8 + hi*4 + 1]) * invlA;
            ra.z = (oA1[rr*4+2] + M[mqA*33 + rr*8 + hi*4 + 2]) * invlA;
            ra.w = (oA1[rr*4+3] + M[mqA*33 + rr*8 + hi*4 + 3]) * invlA;
            rb.x = (oB1[rr*4+0] + M[mqB*33 + rr*8 + hi*4 + 0]) * invlB;
            rb.y = (oB1[rr*4+1] + M[mqB*33 + rr*8 + hi*4 + 1]) * invlB;
            rb.z = (oB1[rr*4+2] + M[mqB*33 + rr*8 + hi*4 + 2]) * invlB;
            rb.w = (oB1[rr*4+3] + M[mqB*33 + rr*8 + hi*4 + 3]) * invlB;
            *reinterpret_cast<float4*>(orowA + rr*8 + hi*4) = ra;
            *reinterpret_cast<float4*>(orowB + rr*8 + hi*4) = rb;
        }
    }
}

extern "C" void kernel_launch(void* const* d_in, const int* in_sizes, int n_in,
                              void* d_out, int out_size, void* d_ws, size_t ws_size,
                              hipStream_t stream) {
    const float* Q = (const float*)d_in[0];
    const float* K = (const float*)d_in[1];
    const float* V = (const float*)d_in[2];
    float* O = (float*)d_out;
    attn_fwd<<<dim3(B_ * (S_ / QB)), dim3(512), 0, stream>>>(Q, K, V, O);
}